// Round 1
// 314.491 us; speedup vs baseline: 1.1344x; 1.1344x over previous
//
#include <hip/hip_runtime.h>

// upfirdn2d: up=(2,2), down=(1,1), pad=((2,1),(2,1)), 4x4 kernel, gain=4
// x: (16,64,128,128) f32 -> out: (16,64,255,255) f32
//
// Output pixel (oy,ox): parity (py,px)=(oy&1,ox&1) picks 4 weights from the
// flipped kernel; input taps at rows iy0,iy0+1, cols ix0,ix0+1 where
// i0 = (o>>1)-1+(o&1). Only i0==-1 at o==0 is OOB (contributes 0).
//
// Strategy (v2): block = 16 output rows of one plane. Stage the 10 needed
// input rows in LDS (aligned float4 writes, stride 132, zero pad at col 3 for
// the ix=-1 tap). Compute phase is COLUMN-MAPPED: thread t owns output column
// ox=t for all 16 rows. Column parity px is fixed per thread -> both weight
// float4s live in registers. Marching down rows, consecutive output rows share
// input rows, so each 2 outputs need only 2 new LDS dwords (one ds_read2_b32,
// 2-way bank access = free). Stores are coalesced global_store_dword
// (64 consecutive lanes per wave = full cache lines).

#define IN_H 128
#define IN_W 128
#define OUT_H 255
#define OUT_W 255
#define ROWS_PER_TILE 16
#define NTILES 16              // ceil(255/16)
#define LDS_STRIDE 132         // data at cols [4..131] = ix 0..127; col 3 = zero pad (ix=-1)
#define MAX_IN_ROWS 10

__global__ __launch_bounds__(256) void upfirdn2d_kernel(
    const float* __restrict__ x,
    const float* __restrict__ k,
    float* __restrict__ out)
{
    __shared__ float lw[16];                       // lw[((py<<1)|px)*4 + (a<<1)|b]
    __shared__ float li[MAX_IN_ROWS * LDS_STRIDE];

    const int tid   = threadIdx.x;
    const int tile  = blockIdx.x;
    const int plane = blockIdx.y;

    const int oy0       = tile * ROWS_PER_TILE;
    const int nrows_out = min(ROWS_PER_TILE, OUT_H - oy0);
    const int iy_lo     = (oy0 >> 1) - 1;                    // 8*tile - 1
    const int iy_hi     = min(IN_H - 1, (oy0 >> 1) + 8);
    const int n_in_rows = iy_hi - iy_lo + 1;                 // 10 (9 on last tile)

    // --- weight table: w[py][px][a][b] = gain * Kflip[sel] ---
    if (tid < 16) {
        const int py = (tid >> 3) & 1;
        const int px = (tid >> 2) & 1;
        const int a  = (tid >> 1) & 1;
        const int b  = tid & 1;
        const int ry = py ? (a ? 0 : 2) : (a ? 1 : 3);
        const int rx = px ? (b ? 0 : 2) : (b ? 1 : 3);
        lw[(((py << 1) | px) << 2) + ((a << 1) | b)] = 4.0f * k[ry * 4 + rx];
    }

    // --- stage input rows iy_lo..iy_hi into LDS (aligned float4 writes) ---
    {
        const float4* xp4 = (const float4*)(x + (size_t)plane * (IN_H * IN_W));
        const int nslots = n_in_rows * (IN_W / 4);           // float4 slots (<=320)
        for (int s = tid; s < nslots; s += 256) {
            const int row = s >> 5;                          // / (128/4)
            const int c4  = s & 31;
            const int iy  = iy_lo + row;
            float4 v = make_float4(0.f, 0.f, 0.f, 0.f);
            if (iy >= 0) v = xp4[iy * (IN_W / 4) + c4];
            *(float4*)&li[row * LDS_STRIDE + 4 + (c4 << 2)] = v;   // 16B aligned
        }
        if (tid < MAX_IN_ROWS) li[tid * LDS_STRIDE + 3] = 0.0f;    // ix=-1 pad
    }
    __syncthreads();

    if (tid >= OUT_W) return;                                // 255 compute lanes

    // --- column-mapped compute: thread = output column ---
    const int px = tid & 1;
    const float4 we = *(const float4*)&lw[px << 2];          // py=0 weights
    const float4 wo = *(const float4*)&lw[(2 | px) << 2];    // py=1 weights
    const int col0 = 3 + (tid >> 1) + px;                    // LDS col of left tap

    // rolling taps: a = input row j, b = row j+1, c = row j+2
    const float* l0 = &li[col0];
    float a0 = l0[0],           a1 = l0[1];
    float b0 = l0[LDS_STRIDE],  b1 = l0[LDS_STRIDE + 1];

    float* op = out + (size_t)plane * (OUT_H * OUT_W) + oy0 * OUT_W + tid;

#pragma unroll
    for (int j = 0; j < 8; ++j) {
        // even output row oy0+2j: taps rows j, j+1
        op[0] = we.x * a0 + we.y * a1 + we.z * b0 + we.w * b1;

        float c0 = 0.f, c1 = 0.f;
        const int r2 = j + 2;
        if (r2 < n_in_rows) {                                // wave-uniform
            const float* lr = &li[r2 * LDS_STRIDE + col0];
            c0 = lr[0]; c1 = lr[1];                          // -> ds_read2_b32
        }

        // odd output row oy0+2j+1: taps rows j+1, j+2
        if (2 * j + 1 < nrows_out) {                         // wave-uniform
            op[OUT_W] = wo.x * b0 + wo.y * b1 + wo.z * c0 + wo.w * c1;
        }

        a0 = b0; a1 = b1; b0 = c0; b1 = c1;
        op += 2 * OUT_W;
    }
}

extern "C" void kernel_launch(void* const* d_in, const int* in_sizes, int n_in,
                              void* d_out, int out_size, void* d_ws, size_t ws_size,
                              hipStream_t stream) {
    const float* x = (const float*)d_in[0];
    const float* k = (const float*)d_in[1];
    float* out = (float*)d_out;

    dim3 block(256, 1, 1);
    dim3 grid(NTILES, 1024, 1);    // tiles-per-plane x planes (16*64)
    upfirdn2d_kernel<<<grid, block, 0, stream>>>(x, k, out);
}